// Round 13
// baseline (307.450 us; speedup 1.0000x reference)
//
#include <hip/hip_runtime.h>
#include <hip/hip_bf16.h>

#define L2E 1.44269504088896340f
#define LN2 0.69314718055994531f

typedef __bf16 bf16x8 __attribute__((ext_vector_type(8)));
typedef __bf16 bf16x4 __attribute__((ext_vector_type(4)));
typedef float f32x4 __attribute__((ext_vector_type(4)));
typedef _Float16 h16x4 __attribute__((ext_vector_type(4)));

__device__ __forceinline__ float fexp2(float x){ return __builtin_amdgcn_exp2f(x); }
__device__ __forceinline__ float flog2(float x){ return __builtin_amdgcn_logf(x); }
__device__ __forceinline__ float frcp(float x){ return __builtin_amdgcn_rcpf(x); }
__device__ __forceinline__ float fsigmoid(float x){ return frcp(1.f + fexp2(-x*L2E)); }
__device__ __forceinline__ float fsoftplus(float x){
  float sp = flog2(1.f + fexp2(x*L2E))*LN2;
  return (x > 15.f) ? x : sp;
}
__device__ __forceinline__ float ftanh_(float x){
  x = fminf(fmaxf(x, -10.f), 10.f);
  float e = fexp2(2.f*L2E*x);
  return (e - 1.f)*frcp(e + 1.f);
}

#define NB 32
#define LS 577
#define DM 192
#define DI 384
#define BL 18464      /* NB*LS */
#define M2T 36928     /* 2*BL */
#define T_CH 37
#define N_CH 16

// ---------------- prep: bf16 casts + alog2 ----------------
__global__ __launch_bounds__(256) void k_prep(
    const float* __restrict__ x,
    const float* __restrict__ fw_in, const float* __restrict__ bw_in,
    const float* __restrict__ fw_out, const float* __restrict__ bw_out,
    const float* __restrict__ fw_xp, const float* __restrict__ bw_xp,
    const float* __restrict__ fw_al, const float* __restrict__ bw_al,
    __hip_bfloat16* __restrict__ xbf, __hip_bfloat16* __restrict__ wcat,
    __hip_bfloat16* __restrict__ wout, __hip_bfloat16* __restrict__ xpp,
    float* __restrict__ alog2)
{
  const int S0 = 3545088;            // xbf  (BL*192)
  const int S1 = S0 + 294912;        // wcat (1536*192)
  const int S2 = S1 + 147456;        // wout (192*768)
  const int S3 = S2 + 24576;         // xpp  (2*32*384)
  const int S4 = S3 + 6144;          // alog2 (2*384*8)
  int idx = blockIdx.x*256 + threadIdx.x;
  if (idx < S0) {
    xbf[idx] = __float2bfloat16(x[idx]);
  } else if (idx < S1) {
    int i = idx - S0; int r = i/192, k = i - r*192;
    float v = (r < 768) ? fw_in[r*192+k] : bw_in[(r-768)*192+k];
    wcat[i] = __float2bfloat16(v);
  } else if (idx < S2) {
    int i = idx - S1; int o = i/768, k = i - o*768;
    float v = 0.5f * ((k < 384) ? fw_out[o*384+k] : bw_out[o*384+(k-384)]);
    wout[i] = __float2bfloat16(v);
  } else if (idx < S3) {
    int i = idx - S2; int d = i/12288; int rr = i - d*12288;
    int n = rr/384, k = rr - n*384;
    const float* xp = d ? bw_xp : fw_xp;
    float v = (n < 28) ? xp[n*384+k] : 0.f;
    xpp[i] = __float2bfloat16(v);
  } else if (idx < S4) {
    int i = idx - S3;
    const float* al = (i < 3072) ? fw_al : bw_al;
    int j = (i < 3072) ? i : (i - 3072);
    alog2[i] = -fexp2(al[j]*L2E) * L2E;   // (-exp(A_log)) * log2(e)
  }
}

// ---------------- GEMM1: LDS-staged 128x128 block tile, K=192 in two 96-halves ----------
#define G1_LDA 104    /* 96 + 8 pad, elems */
#define G1_LDO 136    /* 128 + 8 pad, elems */
__global__ __launch_bounds__(256) void k_gemm1(const __hip_bfloat16* __restrict__ A,
                                               const __hip_bfloat16* __restrict__ Bw,
                                               __hip_bfloat16* __restrict__ xg,
                                               __hip_bfloat16* __restrict__ zsb)
{
  __shared__ __align__(16) __bf16 smem[26624];   // 53248 B
  __bf16* ldsA = smem;
  __bf16* ldsB = smem + 128*G1_LDA;

  const int t = threadIdx.x;
  const int tm = blockIdx.x / 12, tn = blockIdx.x - tm*12;
  const int m0 = tm*128, n0 = tn*128;
  const int w = t >> 6, lane = t & 63;
  const int wr = (w >> 1)*64, wc = (w & 1)*64;
  const int r = lane & 15, q = lane >> 4;

  f32x4 acc[4][4];
  #pragma unroll
  for (int a=0;a<4;++a)
    #pragma unroll
    for (int b=0;b<4;++b) acc[a][b] = (f32x4){0.f,0.f,0.f,0.f};

  #pragma unroll
  for (int h=0; h<2; ++h) {
    if (h) __syncthreads();
    #pragma unroll
    for (int j=0;j<6;++j) {
      int cid = t + 256*j;               // 0..1535
      int row = cid/12; int c8 = (cid - row*12)*8;
      int gr = m0 + row; if (gr > BL-1) gr = BL-1;
      bf16x8 va = *(const bf16x8*)(A + (size_t)gr*192 + h*96 + c8);
      *(bf16x8*)(ldsA + row*G1_LDA + c8) = va;
      bf16x8 vb = *(const bf16x8*)(Bw + (size_t)(n0+row)*192 + h*96 + c8);
      *(bf16x8*)(ldsB + row*G1_LDA + c8) = vb;
    }
    __syncthreads();
    #pragma unroll
    for (int kc=0; kc<96; kc+=32) {
      bf16x8 af[4], bfv[4];
      #pragma unroll
      for (int mi=0; mi<4; ++mi)
        af[mi] = *(const bf16x8*)(ldsA + (wr + mi*16 + r)*G1_LDA + q*8 + kc);
      #pragma unroll
      for (int ni=0; ni<4; ++ni)
        bfv[ni] = *(const bf16x8*)(ldsB + (wc + ni*16 + r)*G1_LDA + q*8 + kc);
      #pragma unroll
      for (int mi=0; mi<4; ++mi)
        #pragma unroll
        for (int ni=0; ni<4; ++ni)
          acc[mi][ni] = __builtin_amdgcn_mfma_f32_16x16x32_bf16(af[mi], bfv[ni], acc[mi][ni], 0,0,0);
    }
  }

  const int cat = tn/3;                   // 0:fw_x 1:fw_z 2:bw_x 3:bw_z
  const int cbase = (tn - cat*3)*128;
  const int d = cat >> 1, isz = cat & 1;
  __syncthreads();
  __bf16* ldsO = smem;
  #pragma unroll
  for (int mi=0; mi<4; ++mi)
    #pragma unroll
    for (int ni=0; ni<4; ++ni)
      #pragma unroll
      for (int rg=0; rg<4; ++rg) {
        int row = wr + mi*16 + q*4 + rg;
        int col = wc + ni*16 + r;
        float v = acc[mi][ni][rg];
        if (isz) v = v * fsigmoid(v);
        ldsO[row*G1_LDO + col] = (__bf16)v;
      }
  __syncthreads();
  __hip_bfloat16* dst = (isz ? zsb : xg) + (size_t)(d*BL)*384 + cbase;
  const int c8 = (t & 15)*8;
  #pragma unroll
  for (int it=0; it<8; ++it) {
    int row = (t >> 4) + it*16;
    int grow = m0 + row;
    if (grow < BL) {
      bf16x8 v = *(const bf16x8*)(ldsO + row*G1_LDO + c8);
      *(bf16x8*)(dst + (size_t)grow*384 + c8) = v;
    }
  }
}

// ---------------- conv + SiLU: xg -> xcs (bf16), 4 channels/thread ----------------
__global__ __launch_bounds__(256) void k_conv(const __hip_bfloat16* __restrict__ xg,
                                              __hip_bfloat16* __restrict__ xcs,
                                              const float* __restrict__ fw_cw, const float* __restrict__ fw_cb,
                                              const float* __restrict__ bw_cw, const float* __restrict__ bw_cb)
{
  int idx = blockIdx.x*256 + threadIdx.x;       // < 2*BL*96
  int token = idx / 96; int g = idx - token*96; int c0 = g*4;
  int d = token / BL; int r2 = token - d*BL;
  int b = r2 / LS; int i = r2 - b*LS;
  const float* cwp = (d ? bw_cw : fw_cw);
  const float* cbp = (d ? bw_cb : fw_cb);
  f32x4 w0 = *(const f32x4*)(cwp + (c0+0)*4);
  f32x4 w1 = *(const f32x4*)(cwp + (c0+1)*4);
  f32x4 w2 = *(const f32x4*)(cwp + (c0+2)*4);
  f32x4 w3 = *(const f32x4*)(cwp + (c0+3)*4);
  f32x4 accv = *(const f32x4*)(cbp + c0);
  const __hip_bfloat16* base = xg + ((size_t)(d*BL + b*LS))*384 + c0;
  #pragma unroll
  for (int j=0;j<4;++j) {
    int iw = d ? (i+3-j) : (i-3+j);
    bool valid = d ? (iw < LS) : (iw >= 0);
    if (valid) {
      bf16x4 xv = *(const bf16x4*)(base + (size_t)iw*384);
      f32x4 wj = (f32x4){w0[j], w1[j], w2[j], w3[j]};
      #pragma unroll
      for (int ch=0; ch<4; ++ch) accv[ch] += wj[ch]*(float)xv[ch];
    }
  }
  bf16x4 outv;
  #pragma unroll
  for (int ch=0; ch<4; ++ch) {
    float s = accv[ch]*fsigmoid(accv[ch]);
    outv[ch] = (__bf16)s;
  }
  *(bf16x4*)(xcs + (size_t)token*384 + c0) = outv;
}

// ---------------- GEMM dt_bc: (M=36928,N=32,K=384), tanh epilogue, scan-order store ----------------
__global__ __launch_bounds__(256) void k_dtbc(const __hip_bfloat16* __restrict__ A,
                                              const __hip_bfloat16* __restrict__ xpp,
                                              float* __restrict__ dtbc)
{
  const int wid = blockIdx.x*4 + (threadIdx.x >> 6);
  if (wid >= 1154) return;
  const int lane = threadIdx.x & 63;
  const int m0 = wid*32;
  const int r = lane & 15, q = lane >> 4;
  const int d = (m0 >= BL) ? 1 : 0;
  const __hip_bfloat16* Bp = xpp + (size_t)d*32*384;
  f32x4 acc[2][2];
  #pragma unroll
  for (int a=0;a<2;++a)
    #pragma unroll
    for (int b=0;b<2;++b) acc[a][b] = (f32x4){0.f,0.f,0.f,0.f};
  const __hip_bfloat16* Ab = A + (size_t)(m0 + r)*384 + q*8;
  const __hip_bfloat16* Bb = Bp + (size_t)r*384 + q*8;
  #pragma unroll
  for (int kc = 0; kc < 384; kc += 32) {
    bf16x8 af0 = *(const bf16x8*)(Ab + kc);
    bf16x8 af1 = *(const bf16x8*)(Ab + 16*384 + kc);
    bf16x8 bf0 = *(const bf16x8*)(Bb + kc);
    bf16x8 bf1 = *(const bf16x8*)(Bb + 16*384 + kc);
    acc[0][0] = __builtin_amdgcn_mfma_f32_16x16x32_bf16(af0, bf0, acc[0][0], 0,0,0);
    acc[0][1] = __builtin_amdgcn_mfma_f32_16x16x32_bf16(af0, bf1, acc[0][1], 0,0,0);
    acc[1][0] = __builtin_amdgcn_mfma_f32_16x16x32_bf16(af1, bf0, acc[1][0], 0,0,0);
    acc[1][1] = __builtin_amdgcn_mfma_f32_16x16x32_bf16(af1, bf1, acc[1][1], 0,0,0);
  }
  #pragma unroll
  for (int mi=0; mi<2; ++mi)
    #pragma unroll
    for (int ni=0; ni<2; ++ni)
      #pragma unroll
      for (int rg=0; rg<4; ++rg) {
        int n = ni*16 + r;
        if (n < 28) {
          int m = m0 + mi*16 + q*4 + rg;
          float v = acc[mi][ni][rg];
          if (n >= 12) v = ftanh_(v);
          int r2 = m - d*BL; int b = r2 / LS; int i = r2 - b*LS;
          int ts = d ? (LS-1-i) : i;
          dtbc[((size_t)((d*NB + b)*LS + ts))*28 + n] = v;
        }
      }
}

// ---------------- dtfull (transposed): thread = channel, loop over m ----------------
__global__ __launch_bounds__(384) void k_dtfull(const float* __restrict__ dtbc,
                                                const float* __restrict__ fw_dtw, const float* __restrict__ fw_dtb,
                                                const float* __restrict__ bw_dtw, const float* __restrict__ bw_dtb,
                                                _Float16* __restrict__ dtf)
{
  const int c = threadIdx.x;           // 0..383
  const int m0 = blockIdx.x*64;        // 577 blocks * 64 = 36928 exactly
  int dcur = -1;
  f32x4 w0, w1, w2; float bias = 0.f;
  for (int i=0; i<64; ++i) {
    int m = m0 + i;
    int d = (m >= BL) ? 1 : 0;
    if (d != dcur) {
      dcur = d;
      const float* wv = (d ? bw_dtw : fw_dtw) + (size_t)c*12;
      w0 = *(const f32x4*)(wv);
      w1 = *(const f32x4*)(wv+4);
      w2 = *(const f32x4*)(wv+8);
      bias = (d ? bw_dtb : fw_dtb)[c];
    }
    const float* dp = dtbc + (size_t)m*28;
    f32x4 p0 = *(const f32x4*)(dp);
    f32x4 p1 = *(const f32x4*)(dp+4);
    f32x4 p2 = *(const f32x4*)(dp+8);
    float s = bias;
    #pragma unroll
    for (int r=0;r<4;++r) s += p0[r]*w0[r];
    #pragma unroll
    for (int r=0;r<4;++r) s += p1[r]*w1[r];
    #pragma unroll
    for (int r=0;r<4;++r) s += p2[r]*w2[r];
    dtf[(size_t)m*384 + c] = (_Float16)(fsoftplus(s) + 1e-4f);
  }
}

// ---------------- scan pass 1: 4 chunks/block, 4-step load batching ----------------
__global__ __launch_bounds__(256) void k_scan1(const __hip_bfloat16* __restrict__ xcs,
                                              const float* __restrict__ dtbc,
                                              const _Float16* __restrict__ dtf,
                                              const float* __restrict__ alog2,
                                              float* __restrict__ ps)
{
  const int lane = threadIdx.x & 63;
  const int bid = blockIdx.x*4 + (threadIdx.x >> 6);
  const int kc = bid & 15; const int dbc = bid >> 4;
  const int cchunk = dbc % 6; const int db = dbc / 6;
  const int b = db & 31; const int d = db >> 5;
  const int c = cchunk*64 + lane;

  const int ts0 = kc*T_CH;
  const int ts1 = (ts0 + T_CH < LS) ? (ts0 + T_CH) : LS;
  const int n = ts1 - ts0;

  float al[8];
  const float* alp = alog2 + ((size_t)(d*384 + c))*8;
  #pragma unroll
  for (int s=0;s<8;++s) al[s] = alp[s];

  const __hip_bfloat16* xcb = xcs + ((size_t)(d*BL + b*LS))*384 + c;
  const _Float16* dfb = dtf + ((size_t)((d*NB+b)*LS))*384 + c;
  const float* dtb_base = dtbc + ((size_t)((d*NB+b)*LS))*28;   // uniform

  const int i0 = d ? (LS-1-ts0) : ts0;
  const int istep = d ? -1 : 1;

  float P[8], S[8];
  #pragma unroll
  for (int s=0;s<8;++s){ P[s]=1.f; S[s]=0.f; }

  int j = 0;
  for (; j+4 <= n; j += 4) {
    float xv[4], dv[4];
    #pragma unroll
    for (int u=0;u<4;++u) {
      int i2 = i0 + (j+u)*istep;
      xv[u] = __bfloat162float(xcb[(size_t)i2*384]);
      dv[u] = (float)dfb[(size_t)(ts0+j+u)*384];
    }
    #pragma unroll
    for (int u=0;u<4;++u) {
      const float* cur = dtb_base + (size_t)(ts0+j+u)*28;
      f32x4 B0 = *(const f32x4*)(cur + 12);
      f32x4 B1 = *(const f32x4*)(cur + 16);
      float xt = xv[u], dt = dv[u];
      #pragma unroll
      for (int s=0;s<8;++s) {
        float da = fexp2(dt * al[s]);
        float Bv = (s<4) ? B0[s] : B1[s-4];
        float tmp = Bv*xt;
        S[s] = tmp + da*(S[s]-tmp);
        P[s] *= da;
      }
    }
  }
  for (; j < n; ++j) {
    int i2 = i0 + j*istep;
    float xt = __bfloat162float(xcb[(size_t)i2*384]);
    float dt = (float)dfb[(size_t)(ts0+j)*384];
    const float* cur = dtb_base + (size_t)(ts0+j)*28;
    f32x4 B0 = *(const f32x4*)(cur + 12);
    f32x4 B1 = *(const f32x4*)(cur + 16);
    #pragma unroll
    for (int s=0;s<8;++s) {
      float da = fexp2(dt * al[s]);
      float Bv = (s<4) ? B0[s] : B1[s-4];
      float tmp = Bv*xt;
      S[s] = tmp + da*(S[s]-tmp);
      P[s] *= da;
    }
  }
  float* pp = ps + ((size_t)bid*16)*64 + lane;
  #pragma unroll
  for (int s=0;s<8;++s) pp[s*64] = P[s];
  #pragma unroll
  for (int s=0;s<8;++s) pp[(8+s)*64] = S[s];
}

// ---------------- combine: stitch chunk states, emit entering state per chunk ----------------
__global__ __launch_bounds__(64) void k_comb(const float* __restrict__ ps,
                                             float* __restrict__ initst)
{
  const int dbc = blockIdx.x;
  const int lane = threadIdx.x;
  float st[8];
  #pragma unroll
  for (int s=0;s<8;++s) st[s]=0.f;
  for (int kc=0;kc<N_CH;++kc) {
    const float* pp = ps + ((size_t)(dbc*N_CH+kc)*16)*64 + lane;
    float* ip = initst + ((size_t)(dbc*N_CH+kc)*8)*64 + lane;
    #pragma unroll
    for (int s=0;s<8;++s) ip[s*64] = st[s];
    #pragma unroll
    for (int s=0;s<8;++s) {
      float P = pp[s*64], Sv = pp[(8+s)*64];
      st[s] = P*st[s] + Sv;
    }
  }
}

// ---------------- scan pass 2: 4 chunks/block, 4-step load batching ----------------
__global__ __launch_bounds__(256) void k_scan2(const __hip_bfloat16* __restrict__ xcs,
                                              const __hip_bfloat16* __restrict__ zsb,
                                              const float* __restrict__ dtbc,
                                              const _Float16* __restrict__ dtf,
                                              const float* __restrict__ initst,
                                              const float* __restrict__ fw_D,
                                              const float* __restrict__ bw_D,
                                              const float* __restrict__ alog2,
                                              __hip_bfloat16* __restrict__ ybf)
{
  const int lane = threadIdx.x & 63;
  const int bid = blockIdx.x*4 + (threadIdx.x >> 6);
  const int kc = bid & 15; const int dbc = bid >> 4;
  const int cchunk = dbc % 6; const int db = dbc / 6;
  const int b = db & 31; const int d = db >> 5;
  const int c = cchunk*64 + lane;

  const int ts0 = kc*T_CH;
  const int ts1 = (ts0 + T_CH < LS) ? (ts0 + T_CH) : LS;
  const int n = ts1 - ts0;

  const float Dc  = (d ? bw_D : fw_D)[c];
  float al[8];
  const float* alp = alog2 + ((size_t)(d*384 + c))*8;
  #pragma unroll
  for (int s=0;s<8;++s) al[s] = alp[s];

  float st[8];
  {
    const float* ip = initst + ((size_t)bid*8)*64 + lane;
    #pragma unroll
    for (int s=0;s<8;++s) st[s] = ip[s*64];
  }

  const __hip_bfloat16* xcb = xcs + ((size_t)(d*BL + b*LS))*384 + c;
  const __hip_bfloat16* zcb = zsb + ((size_t)(d*BL + b*LS))*384 + c;
  const _Float16* dfb = dtf + ((size_t)((d*NB+b)*LS))*384 + c;
  const float* dtb_base = dtbc + ((size_t)((d*NB+b)*LS))*28;   // uniform
  __hip_bfloat16* ybase = ybf + (size_t)(b*LS)*768 + d*384 + c;

  const int i0 = d ? (LS-1-ts0) : ts0;
  const int istep = d ? -1 : 1;

  int j = 0;
  for (; j+4 <= n; j += 4) {
    float xv[4], zv[4], dv[4];
    #pragma unroll
    for (int u=0;u<4;++u) {
      int i2 = i0 + (j+u)*istep;
      xv[u] = __bfloat162float(xcb[(size_t)i2*384]);
      zv[u] = __bfloat162float(zcb[(size_t)i2*384]);
      dv[u] = (float)dfb[(size_t)(ts0+j+u)*384];
    }
    #pragma unroll
    for (int u=0;u<4;++u) {
      const float* cur = dtb_base + (size_t)(ts0+j+u)*28;
      f32x4 B0 = *(const f32x4*)(cur + 12);
      f32x4 B1 = *(const f32x4*)(cur + 16);
      f32x4 C0 = *(const f32x4*)(cur + 20);
      f32x4 C1 = *(const f32x4*)(cur + 24);
      float xt = xv[u], zs = zv[u], dt = dv[u];
      float y = Dc * xt;
      #pragma unroll
      for (int s=0;s<8;++s) {
        float da = fexp2(dt * al[s]);
        float Bv = (s<4) ? B0[s] : B1[s-4];
        float Cv = (s<4) ? C0[s] : C1[s-4];
        float tmp = Bv*xt;
        st[s] = tmp + da*(st[s]-tmp);
        y += st[s]*Cv;
      }
      ybase[(size_t)(i0 + (j+u)*istep)*768] = __float2bfloat16(y*zs);
    }
  }
  for (; j < n; ++j) {
    int i2 = i0 + j*istep;
    float xt = __bfloat162float(xcb[(size_t)i2*384]);
    float zs = __bfloat162float(zcb[(size_t)i2*384]);
    float dt = (float)dfb[(size_t)(ts0+j)*384];
    const float* cur = dtb_base + (size_t)(ts0+j)*28;
    f32x4 B0 = *(const f32x4*)(cur + 12);
    f32x4 B1 = *(const f32x4*)(cur + 16);
    f32x4 C0 = *(const f32x4*)(cur + 20);
    f32x4 C1 = *(const f32x4*)(cur + 24);
    float y = Dc * xt;
    #pragma unroll
    for (int s=0;s<8;++s) {
      float da = fexp2(dt * al[s]);
      float Bv = (s<4) ? B0[s] : B1[s-4];
      float Cv = (s<4) ? C0[s] : C1[s-4];
      float tmp = Bv*xt;
      st[s] = tmp + da*(st[s]-tmp);
      y += st[s]*Cv;
    }
    ybase[(size_t)i2*768] = __float2bfloat16(y*zs);
  }
}

// ---------------- GEMM2: LDS-staged 64x192 block tile, K=768 in eight 96-stages --------
#define G2_LDA 104
__global__ __launch_bounds__(256) void k_gemm2(const __hip_bfloat16* __restrict__ A,
                                               const __hip_bfloat16* __restrict__ Bw,
                                               float* __restrict__ C)
{
  __shared__ __align__(16) __bf16 smem[26624];   // 53248 B: A[64*104] + B[192*104]
  __bf16* ldsA = smem;
  __bf16* ldsB = smem + 64*G2_LDA;

  const int t = threadIdx.x;
  const int m0 = blockIdx.x*64;
  const int w = t >> 6, lane = t & 63;
  const int wr = (w >> 1)*32, wc = (w & 1)*96;
  const int r = lane & 15, q = lane >> 4;

  f32x4 acc[2][6];
  #pragma unroll
  for (int a=0;a<2;++a)
    #pragma unroll
    for (int b=0;b<6;++b) acc[a][b] = (f32x4){0.f,0.f,0.f,0.f};

  #pragma unroll 1
  for (int h=0; h<8; ++h) {
    if (h) __syncthreads();
    #pragma unroll
    for (int j=0;j<3;++j) {
      int cid = t + 256*j;
      int row = cid/12; int c8 = (cid - row*12)*8;
      int gr = m0 + row; if (gr > BL-1) gr = BL-1;
      *(bf16x8*)(ldsA + row*G2_LDA + c8) = *(const bf16x8*)(A + (size_t)gr*768 + h*96 + c8);
    }
    #pragma unroll
    for (int j=0;j<9;++j) {
      int cid = t + 256*j;
      int row = cid/12; int c8 = (cid - row*12)*8;
      *(bf16x8*)(ldsB + row*G2_LDA + c8) = *(const bf16x8*)(Bw + (size_t)row*768 + h*96 + c8);
    }
    __syncthreads();
    #pragma unroll
    for (int kc=0; kc<96; kc+=32) {
      bf16x8 af[2], bfv[6];
      #pragma unroll
      for (int mi=0; mi<2; ++mi)
        af[mi] = *(const bf16x8*)(ldsA + (wr + mi*16 + r)*G2_LDA + q*8 + kc);
      #pragma unroll
      for (int ni=0; ni<6; ++ni)
        bfv[ni] = *(const bf16x8*)(ldsB + (wc + ni*16 + r)*G2_LDA + q*8 + kc);
      #pragma unroll
      for (int mi=0; mi<2; ++mi)
        #pragma unroll
        for (int ni=0; ni<6; ++ni)
          acc[mi][ni] = __builtin_amdgcn_mfma_f32_16x16x32_bf16(af[mi], bfv[ni], acc[mi][ni], 0,0,0);
    }
  }

  #pragma unroll
  for (int mi=0; mi<2; ++mi)
    #pragma unroll
    for (int ni=0; ni<6; ++ni)
      #pragma unroll
      for (int rg=0; rg<4; ++rg) {
        int row = m0 + wr + mi*16 + q*4 + rg;
        int col = wc + ni*16 + r;
        if (row < BL) C[(size_t)row*192 + col] = acc[mi][ni][rg];
      }
}

extern "C" void kernel_launch(void* const* d_in, const int* in_sizes, int n_in,
                              void* d_out, int out_size, void* d_ws, size_t ws_size,
                              hipStream_t stream) {
  const float* x        = (const float*)d_in[0];
  const float* fw_in_w  = (const float*)d_in[1];
  const float* fw_cw    = (const float*)d_in[2];
  const float* fw_cb    = (const float*)d_in[3];
  const float* fw_xp    = (const float*)d_in[4];
  const float* fw_dtw   = (const float*)d_in[5];
  const float* fw_dtb   = (const float*)d_in[6];
  const float* fw_al    = (const float*)d_in[7];
  const float* fw_D     = (const float*)d_in[8];
  const float* fw_ow    = (const float*)d_in[9];
  const float* bw_in_w  = (const float*)d_in[10];
  const float* bw_cw    = (const float*)d_in[11];
  const float* bw_cb    = (const float*)d_in[12];
  const float* bw_xp    = (const float*)d_in[13];
  const float* bw_dtw   = (const float*)d_in[14];
  const float* bw_dtb   = (const float*)d_in[15];
  const float* bw_al    = (const float*)d_in[16];
  const float* bw_D     = (const float*)d_in[17];
  const float* bw_ow    = (const float*)d_in[18];

  char* ws = (char*)d_ws;
  __hip_bfloat16* wcat = (__hip_bfloat16*)(ws + 0);             //   589,824  prep->gemm1
  __hip_bfloat16* wout = (__hip_bfloat16*)(ws + 589824);        //   294,912  prep->gemm2
  __hip_bfloat16* xpp  = (__hip_bfloat16*)(ws + 884736);        //    49,152  prep->dtbc
  float* alog2         = (float*)(ws + 933888);                 //    24,576  prep->scan2
  __hip_bfloat16* xbf  = (__hip_bfloat16*)(ws + 958464);        // 7,090,176  prep->gemm1
  __hip_bfloat16* xg   = (__hip_bfloat16*)(ws + 8048640);       // 28,360,704 gemm1->conv (dead after)
  __hip_bfloat16* ybf  = (__hip_bfloat16*)(ws + 8048640);       // 28,360,704 scan2->gemm2 (over dead xg)
  __hip_bfloat16* zsb  = (__hip_bfloat16*)(ws + 36409344);      // 28,360,704 gemm1->scan2
  __hip_bfloat16* xcs  = (__hip_bfloat16*)(ws + 64770048);      // 28,360,704 conv->scan2
  float* dtbc          = (float*)(ws + 93130752);               //  4,135,936 dtbc->scan2
  _Float16* dtf        = (_Float16*)(ws + 97266688);            // 28,360,704 dtfull->scan2
  float* ps            = (float*)(ws + 125627392);              // 25,165,824 scan1->comb
  float* initst        = (float*)(ws + 150793216);              // 12,582,912 comb->scan2 (end 163,376,128)

  hipLaunchKernelGGL(k_prep, dim3(15696), dim3(256), 0, stream,
                     x, fw_in_w, bw_in_w, fw_ow, bw_ow, fw_xp, bw_xp, fw_al, bw_al,
                     xbf, wcat, wout, xpp, alog2);
  hipLaunchKernelGGL(k_gemm1, dim3(1740), dim3(256), 0, stream, xbf, wcat, xg, zsb);
  hipLaunchKernelGGL(k_conv, dim3(13848), dim3(256), 0, stream,
                     xg, xcs, fw_cw, fw_cb, bw_cw, bw_cb);
  hipLaunchKernelGGL(k_dtbc, dim3(289), dim3(256), 0, stream, xcs, xpp, dtbc);
  hipLaunchKernelGGL(k_dtfull, dim3(577), dim3(384), 0, stream,
                     dtbc, fw_dtw, fw_dtb, bw_dtw, bw_dtb, dtf);
  hipLaunchKernelGGL(k_scan1, dim3(1536), dim3(256), 0, stream,
                     xcs, dtbc, dtf, alog2, ps);
  hipLaunchKernelGGL(k_comb, dim3(384), dim3(64), 0, stream, ps, initst);
  hipLaunchKernelGGL(k_scan2, dim3(1536), dim3(256), 0, stream,
                     xcs, zsb, dtbc, dtf, initst, fw_D, bw_D, alog2, ybf);
  hipLaunchKernelGGL(k_gemm2, dim3(289), dim3(256), 0, stream, ybf, wout, (float*)d_out);
}

// Round 14
// 280.065 us; speedup vs baseline: 1.0978x; 1.0978x over previous
//
#include <hip/hip_runtime.h>
#include <hip/hip_bf16.h>

#define L2E 1.44269504088896340f
#define LN2 0.69314718055994531f

typedef __bf16 bf16x8 __attribute__((ext_vector_type(8)));
typedef __bf16 bf16x4 __attribute__((ext_vector_type(4)));
typedef float f32x4 __attribute__((ext_vector_type(4)));
typedef _Float16 h16x4 __attribute__((ext_vector_type(4)));

__device__ __forceinline__ float fexp2(float x){ return __builtin_amdgcn_exp2f(x); }
__device__ __forceinline__ float flog2(float x){ return __builtin_amdgcn_logf(x); }
__device__ __forceinline__ float frcp(float x){ return __builtin_amdgcn_rcpf(x); }
__device__ __forceinline__ float fsigmoid(float x){ return frcp(1.f + fexp2(-x*L2E)); }
__device__ __forceinline__ float fsoftplus(float x){
  float sp = flog2(1.f + fexp2(x*L2E))*LN2;
  return (x > 15.f) ? x : sp;
}
__device__ __forceinline__ float ftanh_(float x){
  x = fminf(fmaxf(x, -10.f), 10.f);
  float e = fexp2(2.f*L2E*x);
  return (e - 1.f)*frcp(e + 1.f);
}

#define NB 32
#define LS 577
#define DM 192
#define DI 384
#define BL 18464      /* NB*LS */
#define M2T 36928     /* 2*BL */
#define T_CH 37
#define N_CH 16

// ---------------- prep: bf16 casts + alog2 ----------------
__global__ __launch_bounds__(256) void k_prep(
    const float* __restrict__ x,
    const float* __restrict__ fw_in, const float* __restrict__ bw_in,
    const float* __restrict__ fw_out, const float* __restrict__ bw_out,
    const float* __restrict__ fw_xp, const float* __restrict__ bw_xp,
    const float* __restrict__ fw_al, const float* __restrict__ bw_al,
    __hip_bfloat16* __restrict__ xbf, __hip_bfloat16* __restrict__ wcat,
    __hip_bfloat16* __restrict__ wout, __hip_bfloat16* __restrict__ xpp,
    float* __restrict__ alog2)
{
  const int S0 = 3545088;            // xbf  (BL*192)
  const int S1 = S0 + 294912;        // wcat (1536*192)
  const int S2 = S1 + 147456;        // wout (192*768)
  const int S3 = S2 + 24576;         // xpp  (2*32*384)
  const int S4 = S3 + 6144;          // alog2 (2*384*8)
  int idx = blockIdx.x*256 + threadIdx.x;
  if (idx < S0) {
    xbf[idx] = __float2bfloat16(x[idx]);
  } else if (idx < S1) {
    int i = idx - S0; int r = i/192, k = i - r*192;
    float v = (r < 768) ? fw_in[r*192+k] : bw_in[(r-768)*192+k];
    wcat[i] = __float2bfloat16(v);
  } else if (idx < S2) {
    int i = idx - S1; int o = i/768, k = i - o*768;
    float v = 0.5f * ((k < 384) ? fw_out[o*384+k] : bw_out[o*384+(k-384)]);
    wout[i] = __float2bfloat16(v);
  } else if (idx < S3) {
    int i = idx - S2; int d = i/12288; int rr = i - d*12288;
    int n = rr/384, k = rr - n*384;
    const float* xp = d ? bw_xp : fw_xp;
    float v = (n < 28) ? xp[n*384+k] : 0.f;
    xpp[i] = __float2bfloat16(v);
  } else if (idx < S4) {
    int i = idx - S3;
    const float* al = (i < 3072) ? fw_al : bw_al;
    int j = (i < 3072) ? i : (i - 3072);
    alog2[i] = -fexp2(al[j]*L2E) * L2E;   // (-exp(A_log)) * log2(e)
  }
}

// ---------------- GEMM1: LDS-staged 128x128 block tile, K=192 in two 96-halves ----------
#define G1_LDA 104    /* 96 + 8 pad, elems */
#define G1_LDO 136    /* 128 + 8 pad, elems */
__global__ __launch_bounds__(256) void k_gemm1(const __hip_bfloat16* __restrict__ A,
                                               const __hip_bfloat16* __restrict__ Bw,
                                               __hip_bfloat16* __restrict__ xg,
                                               __hip_bfloat16* __restrict__ zsb)
{
  __shared__ __align__(16) __bf16 smem[26624];   // 53248 B
  __bf16* ldsA = smem;
  __bf16* ldsB = smem + 128*G1_LDA;

  const int t = threadIdx.x;
  const int tm = blockIdx.x / 12, tn = blockIdx.x - tm*12;
  const int m0 = tm*128, n0 = tn*128;
  const int w = t >> 6, lane = t & 63;
  const int wr = (w >> 1)*64, wc = (w & 1)*64;
  const int r = lane & 15, q = lane >> 4;

  f32x4 acc[4][4];
  #pragma unroll
  for (int a=0;a<4;++a)
    #pragma unroll
    for (int b=0;b<4;++b) acc[a][b] = (f32x4){0.f,0.f,0.f,0.f};

  #pragma unroll
  for (int h=0; h<2; ++h) {
    if (h) __syncthreads();
    #pragma unroll
    for (int j=0;j<6;++j) {
      int cid = t + 256*j;               // 0..1535
      int row = cid/12; int c8 = (cid - row*12)*8;
      int gr = m0 + row; if (gr > BL-1) gr = BL-1;
      bf16x8 va = *(const bf16x8*)(A + (size_t)gr*192 + h*96 + c8);
      *(bf16x8*)(ldsA + row*G1_LDA + c8) = va;
      bf16x8 vb = *(const bf16x8*)(Bw + (size_t)(n0+row)*192 + h*96 + c8);
      *(bf16x8*)(ldsB + row*G1_LDA + c8) = vb;
    }
    __syncthreads();
    #pragma unroll
    for (int kc=0; kc<96; kc+=32) {
      bf16x8 af[4], bfv[4];
      #pragma unroll
      for (int mi=0; mi<4; ++mi)
        af[mi] = *(const bf16x8*)(ldsA + (wr + mi*16 + r)*G1_LDA + q*8 + kc);
      #pragma unroll
      for (int ni=0; ni<4; ++ni)
        bfv[ni] = *(const bf16x8*)(ldsB + (wc + ni*16 + r)*G1_LDA + q*8 + kc);
      #pragma unroll
      for (int mi=0; mi<4; ++mi)
        #pragma unroll
        for (int ni=0; ni<4; ++ni)
          acc[mi][ni] = __builtin_amdgcn_mfma_f32_16x16x32_bf16(af[mi], bfv[ni], acc[mi][ni], 0,0,0);
    }
  }

  const int cat = tn/3;                   // 0:fw_x 1:fw_z 2:bw_x 3:bw_z
  const int cbase = (tn - cat*3)*128;
  const int d = cat >> 1, isz = cat & 1;
  __syncthreads();
  __bf16* ldsO = smem;
  #pragma unroll
  for (int mi=0; mi<4; ++mi)
    #pragma unroll
    for (int ni=0; ni<4; ++ni)
      #pragma unroll
      for (int rg=0; rg<4; ++rg) {
        int row = wr + mi*16 + q*4 + rg;
        int col = wc + ni*16 + r;
        float v = acc[mi][ni][rg];
        if (isz) v = v * fsigmoid(v);
        ldsO[row*G1_LDO + col] = (__bf16)v;
      }
  __syncthreads();
  __hip_bfloat16* dst = (isz ? zsb : xg) + (size_t)(d*BL)*384 + cbase;
  const int c8 = (t & 15)*8;
  #pragma unroll
  for (int it=0; it<8; ++it) {
    int row = (t >> 4) + it*16;
    int grow = m0 + row;
    if (grow < BL) {
      bf16x8 v = *(const bf16x8*)(ldsO + row*G1_LDO + c8);
      *(bf16x8*)(dst + (size_t)grow*384 + c8) = v;
    }
  }
}

// ---------------- conv + SiLU: xg -> xcs (bf16), 4 channels/thread ----------------
__global__ __launch_bounds__(256) void k_conv(const __hip_bfloat16* __restrict__ xg,
                                              __hip_bfloat16* __restrict__ xcs,
                                              const float* __restrict__ fw_cw, const float* __restrict__ fw_cb,
                                              const float* __restrict__ bw_cw, const float* __restrict__ bw_cb)
{
  int idx = blockIdx.x*256 + threadIdx.x;       // < 2*BL*96
  int token = idx / 96; int g = idx - token*96; int c0 = g*4;
  int d = token / BL; int r2 = token - d*BL;
  int b = r2 / LS; int i = r2 - b*LS;
  const float* cwp = (d ? bw_cw : fw_cw);
  const float* cbp = (d ? bw_cb : fw_cb);
  f32x4 w0 = *(const f32x4*)(cwp + (c0+0)*4);
  f32x4 w1 = *(const f32x4*)(cwp + (c0+1)*4);
  f32x4 w2 = *(const f32x4*)(cwp + (c0+2)*4);
  f32x4 w3 = *(const f32x4*)(cwp + (c0+3)*4);
  f32x4 accv = *(const f32x4*)(cbp + c0);
  const __hip_bfloat16* base = xg + ((size_t)(d*BL + b*LS))*384 + c0;
  #pragma unroll
  for (int j=0;j<4;++j) {
    int iw = d ? (i+3-j) : (i-3+j);
    bool valid = d ? (iw < LS) : (iw >= 0);
    if (valid) {
      bf16x4 xv = *(const bf16x4*)(base + (size_t)iw*384);
      f32x4 wj = (f32x4){w0[j], w1[j], w2[j], w3[j]};
      #pragma unroll
      for (int ch=0; ch<4; ++ch) accv[ch] += wj[ch]*(float)xv[ch];
    }
  }
  bf16x4 outv;
  #pragma unroll
  for (int ch=0; ch<4; ++ch) {
    float s = accv[ch]*fsigmoid(accv[ch]);
    outv[ch] = (__bf16)s;
  }
  *(bf16x4*)(xcs + (size_t)token*384 + c0) = outv;
}

// ---------------- GEMM dt_bc: (M=36928,N=32,K=384), tanh epilogue, scan-order store ----------------
__global__ __launch_bounds__(256) void k_dtbc(const __hip_bfloat16* __restrict__ A,
                                              const __hip_bfloat16* __restrict__ xpp,
                                              float* __restrict__ dtbc)
{
  const int wid = blockIdx.x*4 + (threadIdx.x >> 6);
  if (wid >= 1154) return;
  const int lane = threadIdx.x & 63;
  const int m0 = wid*32;
  const int r = lane & 15, q = lane >> 4;
  const int d = (m0 >= BL) ? 1 : 0;
  const __hip_bfloat16* Bp = xpp + (size_t)d*32*384;
  f32x4 acc[2][2];
  #pragma unroll
  for (int a=0;a<2;++a)
    #pragma unroll
    for (int b=0;b<2;++b) acc[a][b] = (f32x4){0.f,0.f,0.f,0.f};
  const __hip_bfloat16* Ab = A + (size_t)(m0 + r)*384 + q*8;
  const __hip_bfloat16* Bb = Bp + (size_t)r*384 + q*8;
  #pragma unroll
  for (int kc = 0; kc < 384; kc += 32) {
    bf16x8 af0 = *(const bf16x8*)(Ab + kc);
    bf16x8 af1 = *(const bf16x8*)(Ab + 16*384 + kc);
    bf16x8 bf0 = *(const bf16x8*)(Bb + kc);
    bf16x8 bf1 = *(const bf16x8*)(Bb + 16*384 + kc);
    acc[0][0] = __builtin_amdgcn_mfma_f32_16x16x32_bf16(af0, bf0, acc[0][0], 0,0,0);
    acc[0][1] = __builtin_amdgcn_mfma_f32_16x16x32_bf16(af0, bf1, acc[0][1], 0,0,0);
    acc[1][0] = __builtin_amdgcn_mfma_f32_16x16x32_bf16(af1, bf0, acc[1][0], 0,0,0);
    acc[1][1] = __builtin_amdgcn_mfma_f32_16x16x32_bf16(af1, bf1, acc[1][1], 0,0,0);
  }
  #pragma unroll
  for (int mi=0; mi<2; ++mi)
    #pragma unroll
    for (int ni=0; ni<2; ++ni)
      #pragma unroll
      for (int rg=0; rg<4; ++rg) {
        int n = ni*16 + r;
        if (n < 28) {
          int m = m0 + mi*16 + q*4 + rg;
          float v = acc[mi][ni][rg];
          if (n >= 12) v = ftanh_(v);
          int r2 = m - d*BL; int b = r2 / LS; int i = r2 - b*LS;
          int ts = d ? (LS-1-i) : i;
          dtbc[((size_t)((d*NB + b)*LS + ts))*28 + n] = v;
        }
      }
}

// ---------------- dtfull (transposed): thread = channel, loop over m ----------------
__global__ __launch_bounds__(384) void k_dtfull(const float* __restrict__ dtbc,
                                                const float* __restrict__ fw_dtw, const float* __restrict__ fw_dtb,
                                                const float* __restrict__ bw_dtw, const float* __restrict__ bw_dtb,
                                                _Float16* __restrict__ dtf)
{
  const int c = threadIdx.x;           // 0..383
  const int m0 = blockIdx.x*64;        // 577 blocks * 64 = 36928 exactly
  int dcur = -1;
  f32x4 w0, w1, w2; float bias = 0.f;
  for (int i=0; i<64; ++i) {
    int m = m0 + i;
    int d = (m >= BL) ? 1 : 0;
    if (d != dcur) {
      dcur = d;
      const float* wv = (d ? bw_dtw : fw_dtw) + (size_t)c*12;
      w0 = *(const f32x4*)(wv);
      w1 = *(const f32x4*)(wv+4);
      w2 = *(const f32x4*)(wv+8);
      bias = (d ? bw_dtb : fw_dtb)[c];
    }
    const float* dp = dtbc + (size_t)m*28;
    f32x4 p0 = *(const f32x4*)(dp);
    f32x4 p1 = *(const f32x4*)(dp+4);
    f32x4 p2 = *(const f32x4*)(dp+8);
    float s = bias;
    #pragma unroll
    for (int r=0;r<4;++r) s += p0[r]*w0[r];
    #pragma unroll
    for (int r=0;r<4;++r) s += p1[r]*w1[r];
    #pragma unroll
    for (int r=0;r<4;++r) s += p2[r]*w2[r];
    dtf[(size_t)m*384 + c] = (_Float16)(fsoftplus(s) + 1e-4f);
  }
}

// ---------------- scan pass 1: 64-thread blocks (uniform blockIdx), 4-step batching ----
__global__ __launch_bounds__(64) void k_scan1(const __hip_bfloat16* __restrict__ xcs,
                                              const float* __restrict__ dtbc,
                                              const _Float16* __restrict__ dtf,
                                              const float* __restrict__ alog2,
                                              float* __restrict__ ps)
{
  const int bid = blockIdx.x;
  const int lane = threadIdx.x;
  const int kc = bid & 15; const int dbc = bid >> 4;
  const int cchunk = dbc % 6; const int db = dbc / 6;
  const int b = db & 31; const int d = db >> 5;
  const int c = cchunk*64 + lane;

  const int ts0 = kc*T_CH;
  const int ts1 = (ts0 + T_CH < LS) ? (ts0 + T_CH) : LS;
  const int n = ts1 - ts0;

  float al[8];
  const float* alp = alog2 + ((size_t)(d*384 + c))*8;
  #pragma unroll
  for (int s=0;s<8;++s) al[s] = alp[s];

  const __hip_bfloat16* xcb = xcs + ((size_t)(d*BL + b*LS))*384 + c;
  const _Float16* dfb = dtf + ((size_t)((d*NB+b)*LS))*384 + c;
  const float* dtb_base = dtbc + ((size_t)((d*NB+b)*LS))*28;   // uniform

  const int i0 = d ? (LS-1-ts0) : ts0;
  const int istep = d ? -1 : 1;

  float P[8], S[8];
  #pragma unroll
  for (int s=0;s<8;++s){ P[s]=1.f; S[s]=0.f; }

  int j = 0;
  for (; j+4 <= n; j += 4) {
    float xv[4], dv[4];
    #pragma unroll
    for (int u=0;u<4;++u) {
      int i2 = i0 + (j+u)*istep;
      xv[u] = __bfloat162float(xcb[(size_t)i2*384]);
      dv[u] = (float)dfb[(size_t)(ts0+j+u)*384];
    }
    #pragma unroll
    for (int u=0;u<4;++u) {
      const float* cur = dtb_base + (size_t)(ts0+j+u)*28;   // uniform
      f32x4 B0 = *(const f32x4*)(cur + 12);
      f32x4 B1 = *(const f32x4*)(cur + 16);
      float xt = xv[u], dt = dv[u];
      #pragma unroll
      for (int s=0;s<8;++s) {
        float da = fexp2(dt * al[s]);
        float Bv = (s<4) ? B0[s] : B1[s-4];
        float tmp = Bv*xt;
        S[s] = tmp + da*(S[s]-tmp);
        P[s] *= da;
      }
    }
  }
  for (; j < n; ++j) {
    int i2 = i0 + j*istep;
    float xt = __bfloat162float(xcb[(size_t)i2*384]);
    float dt = (float)dfb[(size_t)(ts0+j)*384];
    const float* cur = dtb_base + (size_t)(ts0+j)*28;
    f32x4 B0 = *(const f32x4*)(cur + 12);
    f32x4 B1 = *(const f32x4*)(cur + 16);
    #pragma unroll
    for (int s=0;s<8;++s) {
      float da = fexp2(dt * al[s]);
      float Bv = (s<4) ? B0[s] : B1[s-4];
      float tmp = Bv*xt;
      S[s] = tmp + da*(S[s]-tmp);
      P[s] *= da;
    }
  }
  float* pp = ps + ((size_t)bid*16)*64 + lane;
  #pragma unroll
  for (int s=0;s<8;++s) pp[s*64] = P[s];
  #pragma unroll
  for (int s=0;s<8;++s) pp[(8+s)*64] = S[s];
}

// ---------------- combine: stitch chunk states, emit entering state per chunk ----------------
__global__ __launch_bounds__(64) void k_comb(const float* __restrict__ ps,
                                             float* __restrict__ initst)
{
  const int dbc = blockIdx.x;
  const int lane = threadIdx.x;
  float st[8];
  #pragma unroll
  for (int s=0;s<8;++s) st[s]=0.f;
  for (int kc=0;kc<N_CH;++kc) {
    const float* pp = ps + ((size_t)(dbc*N_CH+kc)*16)*64 + lane;
    float* ip = initst + ((size_t)(dbc*N_CH+kc)*8)*64 + lane;
    #pragma unroll
    for (int s=0;s<8;++s) ip[s*64] = st[s];
    #pragma unroll
    for (int s=0;s<8;++s) {
      float P = pp[s*64], Sv = pp[(8+s)*64];
      st[s] = P*st[s] + Sv;
    }
  }
}

// ---------------- scan pass 2: 64-thread blocks (uniform blockIdx), 4-step batching ----
__global__ __launch_bounds__(64) void k_scan2(const __hip_bfloat16* __restrict__ xcs,
                                              const __hip_bfloat16* __restrict__ zsb,
                                              const float* __restrict__ dtbc,
                                              const _Float16* __restrict__ dtf,
                                              const float* __restrict__ initst,
                                              const float* __restrict__ fw_D,
                                              const float* __restrict__ bw_D,
                                              const float* __restrict__ alog2,
                                              __hip_bfloat16* __restrict__ ybf)
{
  const int bid = blockIdx.x;
  const int lane = threadIdx.x;
  const int kc = bid & 15; const int dbc = bid >> 4;
  const int cchunk = dbc % 6; const int db = dbc / 6;
  const int b = db & 31; const int d = db >> 5;
  const int c = cchunk*64 + lane;

  const int ts0 = kc*T_CH;
  const int ts1 = (ts0 + T_CH < LS) ? (ts0 + T_CH) : LS;
  const int n = ts1 - ts0;

  const float Dc  = (d ? bw_D : fw_D)[c];
  float al[8];
  const float* alp = alog2 + ((size_t)(d*384 + c))*8;
  #pragma unroll
  for (int s=0;s<8;++s) al[s] = alp[s];

  float st[8];
  {
    const float* ip = initst + ((size_t)bid*8)*64 + lane;
    #pragma unroll
    for (int s=0;s<8;++s) st[s] = ip[s*64];
  }

  const __hip_bfloat16* xcb = xcs + ((size_t)(d*BL + b*LS))*384 + c;
  const __hip_bfloat16* zcb = zsb + ((size_t)(d*BL + b*LS))*384 + c;
  const _Float16* dfb = dtf + ((size_t)((d*NB+b)*LS))*384 + c;
  const float* dtb_base = dtbc + ((size_t)((d*NB+b)*LS))*28;   // uniform
  __hip_bfloat16* ybase = ybf + (size_t)(b*LS)*768 + d*384 + c;

  const int i0 = d ? (LS-1-ts0) : ts0;
  const int istep = d ? -1 : 1;

  int j = 0;
  for (; j+4 <= n; j += 4) {
    float xv[4], zv[4], dv[4];
    #pragma unroll
    for (int u=0;u<4;++u) {
      int i2 = i0 + (j+u)*istep;
      xv[u] = __bfloat162float(xcb[(size_t)i2*384]);
      zv[u] = __bfloat162float(zcb[(size_t)i2*384]);
      dv[u] = (float)dfb[(size_t)(ts0+j+u)*384];
    }
    #pragma unroll
    for (int u=0;u<4;++u) {
      const float* cur = dtb_base + (size_t)(ts0+j+u)*28;   // uniform
      f32x4 B0 = *(const f32x4*)(cur + 12);
      f32x4 B1 = *(const f32x4*)(cur + 16);
      f32x4 C0 = *(const f32x4*)(cur + 20);
      f32x4 C1 = *(const f32x4*)(cur + 24);
      float xt = xv[u], zs = zv[u], dt = dv[u];
      float y = Dc * xt;
      #pragma unroll
      for (int s=0;s<8;++s) {
        float da = fexp2(dt * al[s]);
        float Bv = (s<4) ? B0[s] : B1[s-4];
        float Cv = (s<4) ? C0[s] : C1[s-4];
        float tmp = Bv*xt;
        st[s] = tmp + da*(st[s]-tmp);
        y += st[s]*Cv;
      }
      ybase[(size_t)(i0 + (j+u)*istep)*768] = __float2bfloat16(y*zs);
    }
  }
  for (; j < n; ++j) {
    int i2 = i0 + j*istep;
    float xt = __bfloat162float(xcb[(size_t)i2*384]);
    float zs = __bfloat162float(zcb[(size_t)i2*384]);
    float dt = (float)dfb[(size_t)(ts0+j)*384];
    const float* cur = dtb_base + (size_t)(ts0+j)*28;
    f32x4 B0 = *(const f32x4*)(cur + 12);
    f32x4 B1 = *(const f32x4*)(cur + 16);
    f32x4 C0 = *(const f32x4*)(cur + 20);
    f32x4 C1 = *(const f32x4*)(cur + 24);
    float y = Dc * xt;
    #pragma unroll
    for (int s=0;s<8;++s) {
      float da = fexp2(dt * al[s]);
      float Bv = (s<4) ? B0[s] : B1[s-4];
      float Cv = (s<4) ? C0[s] : C1[s-4];
      float tmp = Bv*xt;
      st[s] = tmp + da*(st[s]-tmp);
      y += st[s]*Cv;
    }
    ybase[(size_t)i2*768] = __float2bfloat16(y*zs);
  }
}

// ---------------- GEMM2: LDS-staged 64x192 block tile, K=768 in eight 96-stages --------
#define G2_LDA 104
__global__ __launch_bounds__(256) void k_gemm2(const __hip_bfloat16* __restrict__ A,
                                               const __hip_bfloat16* __restrict__ Bw,
                                               float* __restrict__ C)
{
  __shared__ __align__(16) __bf16 smem[26624];   // 53248 B: A[64*104] + B[192*104]
  __bf16* ldsA = smem;
  __bf16* ldsB = smem + 64*G2_LDA;

  const int t = threadIdx.x;
  const int m0 = blockIdx.x*64;
  const int w = t >> 6, lane = t & 63;
  const int wr = (w >> 1)*32, wc = (w & 1)*96;
  const int r = lane & 15, q = lane >> 4;

  f32x4 acc[2][6];
  #pragma unroll
  for (int a=0;a<2;++a)
    #pragma unroll
    for (int b=0;b<6;++b) acc[a][b] = (f32x4){0.f,0.f,0.f,0.f};

  #pragma unroll 1
  for (int h=0; h<8; ++h) {
    if (h) __syncthreads();
    #pragma unroll
    for (int j=0;j<3;++j) {
      int cid = t + 256*j;
      int row = cid/12; int c8 = (cid - row*12)*8;
      int gr = m0 + row; if (gr > BL-1) gr = BL-1;
      *(bf16x8*)(ldsA + row*G2_LDA + c8) = *(const bf16x8*)(A + (size_t)gr*768 + h*96 + c8);
    }
    #pragma unroll
    for (int j=0;j<9;++j) {
      int cid = t + 256*j;
      int row = cid/12; int c8 = (cid - row*12)*8;
      *(bf16x8*)(ldsB + row*G2_LDA + c8) = *(const bf16x8*)(Bw + (size_t)row*768 + h*96 + c8);
    }
    __syncthreads();
    #pragma unroll
    for (int kc=0; kc<96; kc+=32) {
      bf16x8 af[2], bfv[6];
      #pragma unroll
      for (int mi=0; mi<2; ++mi)
        af[mi] = *(const bf16x8*)(ldsA + (wr + mi*16 + r)*G2_LDA + q*8 + kc);
      #pragma unroll
      for (int ni=0; ni<6; ++ni)
        bfv[ni] = *(const bf16x8*)(ldsB + (wc + ni*16 + r)*G2_LDA + q*8 + kc);
      #pragma unroll
      for (int mi=0; mi<2; ++mi)
        #pragma unroll
        for (int ni=0; ni<6; ++ni)
          acc[mi][ni] = __builtin_amdgcn_mfma_f32_16x16x32_bf16(af[mi], bfv[ni], acc[mi][ni], 0,0,0);
    }
  }

  #pragma unroll
  for (int mi=0; mi<2; ++mi)
    #pragma unroll
    for (int ni=0; ni<6; ++ni)
      #pragma unroll
      for (int rg=0; rg<4; ++rg) {
        int row = m0 + wr + mi*16 + q*4 + rg;
        int col = wc + ni*16 + r;
        if (row < BL) C[(size_t)row*192 + col] = acc[mi][ni][rg];
      }
}

extern "C" void kernel_launch(void* const* d_in, const int* in_sizes, int n_in,
                              void* d_out, int out_size, void* d_ws, size_t ws_size,
                              hipStream_t stream) {
  const float* x        = (const float*)d_in[0];
  const float* fw_in_w  = (const float*)d_in[1];
  const float* fw_cw    = (const float*)d_in[2];
  const float* fw_cb    = (const float*)d_in[3];
  const float* fw_xp    = (const float*)d_in[4];
  const float* fw_dtw   = (const float*)d_in[5];
  const float* fw_dtb   = (const float*)d_in[6];
  const float* fw_al    = (const float*)d_in[7];
  const float* fw_D     = (const float*)d_in[8];
  const float* fw_ow    = (const float*)d_in[9];
  const float* bw_in_w  = (const float*)d_in[10];
  const float* bw_cw    = (const float*)d_in[11];
  const float* bw_cb    = (const float*)d_in[12];
  const float* bw_xp    = (const float*)d_in[13];
  const float* bw_dtw   = (const float*)d_in[14];
  const float* bw_dtb   = (const float*)d_in[15];
  const float* bw_al    = (const float*)d_in[16];
  const float* bw_D     = (const float*)d_in[17];
  const float* bw_ow    = (const float*)d_in[18];

  char* ws = (char*)d_ws;
  __hip_bfloat16* wcat = (__hip_bfloat16*)(ws + 0);             //   589,824  prep->gemm1
  __hip_bfloat16* wout = (__hip_bfloat16*)(ws + 589824);        //   294,912  prep->gemm2
  __hip_bfloat16* xpp  = (__hip_bfloat16*)(ws + 884736);        //    49,152  prep->dtbc
  float* alog2         = (float*)(ws + 933888);                 //    24,576  prep->scan2
  __hip_bfloat16* xbf  = (__hip_bfloat16*)(ws + 958464);        // 7,090,176  prep->gemm1
  __hip_bfloat16* xg   = (__hip_bfloat16*)(ws + 8048640);       // 28,360,704 gemm1->conv (dead after)
  __hip_bfloat16* ybf  = (__hip_bfloat16*)(ws + 8048640);       // 28,360,704 scan2->gemm2 (over dead xg)
  __hip_bfloat16* zsb  = (__hip_bfloat16*)(ws + 36409344);      // 28,360,704 gemm1->scan2
  __hip_bfloat16* xcs  = (__hip_bfloat16*)(ws + 64770048);      // 28,360,704 conv->scan2
  float* dtbc          = (float*)(ws + 93130752);               //  4,135,936 dtbc->scan2
  _Float16* dtf        = (_Float16*)(ws + 97266688);            // 28,360,704 dtfull->scan2
  float* ps            = (float*)(ws + 125627392);              // 25,165,824 scan1->comb
  float* initst        = (float*)(ws + 150793216);              // 12,582,912 comb->scan2 (end 163,376,128)

  hipLaunchKernelGGL(k_prep, dim3(15696), dim3(256), 0, stream,
                     x, fw_in_w, bw_in_w, fw_ow, bw_ow, fw_xp, bw_xp, fw_al, bw_al,
                     xbf, wcat, wout, xpp, alog2);
  hipLaunchKernelGGL(k_gemm1, dim3(1740), dim3(256), 0, stream, xbf, wcat, xg, zsb);
  hipLaunchKernelGGL(k_conv, dim3(13848), dim3(256), 0, stream,
                     xg, xcs, fw_cw, fw_cb, bw_cw, bw_cb);
  hipLaunchKernelGGL(k_dtbc, dim3(289), dim3(256), 0, stream, xcs, xpp, dtbc);
  hipLaunchKernelGGL(k_dtfull, dim3(577), dim3(384), 0, stream,
                     dtbc, fw_dtw, fw_dtb, bw_dtw, bw_dtb, dtf);
  hipLaunchKernelGGL(k_scan1, dim3(6144), dim3(64), 0, stream,
                     xcs, dtbc, dtf, alog2, ps);
  hipLaunchKernelGGL(k_comb, dim3(384), dim3(64), 0, stream, ps, initst);
  hipLaunchKernelGGL(k_scan2, dim3(6144), dim3(64), 0, stream,
                     xcs, zsb, dtbc, dtf, initst, fw_D, bw_D, alog2, ybf);
  hipLaunchKernelGGL(k_gemm2, dim3(289), dim3(256), 0, stream, ybf, wout, (float*)d_out);
}